// Round 1
// baseline (118.709 us; speedup 1.0000x reference)
//
#include <hip/hip_runtime.h>
#include <hip/hip_bf16.h>
#include <math.h>

#define N_NODES 2048
#define F_DIM   128
#define H_HEADS 4
#define B_BATCH 8
#define LEAKY   0.2f

__device__ __forceinline__ float tanh_fast(float x) {
    const float e = __expf(2.0f * x);
    return 1.0f - 2.0f / (e + 1.0f);
}

// ---------------- Kernel 1: projections, packed [b][n][h] ----------------
__global__ __launch_bounds__(256) void gat_proj(const float* __restrict__ X,
                                                const float* __restrict__ wS,
                                                const float* __restrict__ wN,
                                                float* __restrict__ aSt,
                                                float* __restrict__ aNt) {
    const int wave = threadIdx.x >> 6;
    const int lane = threadIdx.x & 63;
    const int row  = blockIdx.x * 4 + wave;            // b*N + n
    const float* xr = X + (size_t)row * F_DIM;
    const float x0 = xr[lane];
    const float x1 = xr[lane + 64];
    float4 ps4, pn4;
    float* psv = (float*)&ps4;
    float* pnv = (float*)&pn4;
#pragma unroll
    for (int h = 0; h < H_HEADS; ++h) {
        float ps = x0 * wS[h * F_DIM + lane] + x1 * wS[h * F_DIM + 64 + lane];
        float pn = x0 * wN[h * F_DIM + lane] + x1 * wN[h * F_DIM + 64 + lane];
#pragma unroll
        for (int off = 32; off > 0; off >>= 1) {
            ps += __shfl_xor(ps, off);
            pn += __shfl_xor(pn, off);
        }
        psv[h] = ps;
        pnv[h] = pn;
    }
    if (lane == 0) {
        ((float4*)aSt)[row] = ps4;
        ((float4*)aNt)[row] = pn4;
    }
}

// ---------------- Kernel 1b: per-(b,h) global max of a_neigh ----------------
__global__ __launch_bounds__(256) void gat_gmax(const float* __restrict__ aNt,
                                                float* __restrict__ gmax) {
    const int b = blockIdx.x;
    const int tid = threadIdx.x;
    const int lane = tid & 63;
    const int wv = tid >> 6;
    __shared__ float4 s_part[4];
    float4 m = make_float4(-1e30f, -1e30f, -1e30f, -1e30f);
    const float4* src = (const float4*)aNt + (size_t)b * N_NODES;
    for (int n = tid; n < N_NODES; n += 256) {
        const float4 v = src[n];
        m.x = fmaxf(m.x, v.x); m.y = fmaxf(m.y, v.y);
        m.z = fmaxf(m.z, v.z); m.w = fmaxf(m.w, v.w);
    }
#pragma unroll
    for (int off = 32; off > 0; off >>= 1) {
        m.x = fmaxf(m.x, __shfl_xor(m.x, off));
        m.y = fmaxf(m.y, __shfl_xor(m.y, off));
        m.z = fmaxf(m.z, __shfl_xor(m.z, off));
        m.w = fmaxf(m.w, __shfl_xor(m.w, off));
    }
    if (lane == 0) s_part[wv] = m;
    __syncthreads();
    if (tid == 0) {
        float4 r = s_part[0];
#pragma unroll
        for (int w = 1; w < 4; ++w) {
            r.x = fmaxf(r.x, s_part[w].x); r.y = fmaxf(r.y, s_part[w].y);
            r.z = fmaxf(r.z, s_part[w].z); r.w = fmaxf(r.w, s_part[w].w);
        }
        ((float4*)gmax)[b] = r;
    }
}

// 16-FMA microtile: 4 heads x 4 feature floats
#define FMA16(PV, XV)                                        \
    do {                                                     \
        acc[0][0] = fmaf((PV).x, (XV).x, acc[0][0]);         \
        acc[0][1] = fmaf((PV).x, (XV).y, acc[0][1]);         \
        acc[0][2] = fmaf((PV).x, (XV).z, acc[0][2]);         \
        acc[0][3] = fmaf((PV).x, (XV).w, acc[0][3]);         \
        acc[1][0] = fmaf((PV).y, (XV).x, acc[1][0]);         \
        acc[1][1] = fmaf((PV).y, (XV).y, acc[1][1]);         \
        acc[1][2] = fmaf((PV).y, (XV).z, acc[1][2]);         \
        acc[1][3] = fmaf((PV).y, (XV).w, acc[1][3]);         \
        acc[2][0] = fmaf((PV).z, (XV).x, acc[2][0]);         \
        acc[2][1] = fmaf((PV).z, (XV).y, acc[2][1]);         \
        acc[2][2] = fmaf((PV).z, (XV).z, acc[2][2]);         \
        acc[2][3] = fmaf((PV).z, (XV).w, acc[2][3]);         \
        acc[3][0] = fmaf((PV).w, (XV).x, acc[3][0]);         \
        acc[3][1] = fmaf((PV).w, (XV).y, acc[3][1]);         \
        acc[3][2] = fmaf((PV).w, (XV).z, acc[3][2]);         \
        acc[3][3] = fmaf((PV).w, (XV).w, acc[3][3]);         \
    } while (0)

// ---------------- Kernel 2: sparse softmax-gather per (b,n) row ----------------
__global__ __launch_bounds__(256, 8) void gat_main(const float* __restrict__ X,
                                                   const float* __restrict__ A,
                                                   const float* __restrict__ aSt,
                                                   const float* __restrict__ aNt,
                                                   const float* __restrict__ gmax,
                                                   float* __restrict__ out) {
    const int tid = threadIdx.x;
    const int row = blockIdx.x;                 // b*N + n
    const int b = row >> 11;
    const int lane = tid & 63;
    const int wv = tid >> 6;

    __shared__ short  s_idx[N_NODES];           // compacted neighbor indices (sorted)
    __shared__ float4 s_p4[272];                // p for chunk: [entry][head], +16 zero pad
    __shared__ int    s_off[272];               // X-row byte offsets, +16 zero pad
    __shared__ float  s_red[4 * 512];           // per-wave partial sums
    __shared__ int    s_wtot[4];
    __shared__ float  s_M[4];
    __shared__ float  s_sv[4];
    __shared__ float  s_scr[16];                // [wv][h] lsum partials

    // ---- Phase 1: scan A row, prefix-sum compact nonzero columns ----
    const float4* Arow = (const float4*)(A + (size_t)row * N_NODES);
    const float4 a0 = Arow[tid * 2];
    const float4 a1 = Arow[tid * 2 + 1];

    // per-head shift constants (independent; overlaps A-load latency)
    if (tid < 4) {
        const float sv = aSt[(size_t)row * 4 + tid];
        const float g = gmax[b * 4 + tid];
        float v = sv + g;
        v = fmaxf(v, LEAKY * v);                // leaky, monotonic -> valid upper bound
        s_M[tid] = v;
        s_sv[tid] = sv;
    }

    const float av[8] = {a0.x, a0.y, a0.z, a0.w, a1.x, a1.y, a1.z, a1.w};
    int c = 0;
#pragma unroll
    for (int k = 0; k < 8; ++k) c += (av[k] != 0.0f) ? 1 : 0;

    int incl = c;
#pragma unroll
    for (int d = 1; d < 64; d <<= 1) {
        const int u = __shfl_up(incl, d);
        if (lane >= d) incl += u;
    }
    if (lane == 63) s_wtot[wv] = incl;
    __syncthreads();
    int wbase = 0;
#pragma unroll
    for (int w = 0; w < 4; ++w) wbase += (w < wv) ? s_wtot[w] : 0;
    const int cnt = s_wtot[0] + s_wtot[1] + s_wtot[2] + s_wtot[3];
    int pos = wbase + (incl - c);
#pragma unroll
    for (int k = 0; k < 8; ++k) {
        if (av[k] != 0.0f) s_idx[pos++] = (short)(tid * 8 + k);
    }
    __syncthreads();

    // ---- Phase 2: chunked p-generation + software-pipelined gather ----
    float acc[4][4];
#pragma unroll
    for (int h = 0; h < 4; ++h)
#pragma unroll
        for (int fi = 0; fi < 4; ++fi) acc[h][fi] = 0.0f;
    float lsum[4] = {0.0f, 0.0f, 0.0f, 0.0f};

    const int jsub = tid >> 5;                  // 0..7
    const int f4 = tid & 31;                    // 0..31
    const char* XbB = (const char*)(X + (size_t)b * N_NODES * F_DIM) + (f4 << 4);
    const float4* aNb4 = (const float4*)aNt + (size_t)b * N_NODES;

    for (int base = 0; base < cnt; base += 256) {
        const int clen = min(256, cnt - base);
        const int plen = (clen + 7) & ~7;       // pad chunk to multiple of 8

        // stage-0 X row prefetch: issue BEFORE p-gen so latency hides under it
        const int pj = (jsub < clen) ? (int)s_idx[base + jsub] : 0;
        const float4 xv_pre = *(const float4*)(XbB + ((unsigned)pj << 9));

        if (tid < plen) {
            float4 p4;
            int offv;
            if (tid < clen) {
                const int m = s_idx[base + tid];
                const float4 t = aNb4[m];
                const float tv[4] = {t.x, t.y, t.z, t.w};
                float* pp = (float*)&p4;
#pragma unroll
                for (int h = 0; h < H_HEADS; ++h) {
                    float v = s_sv[h] + tv[h];
                    v = fmaxf(v, LEAKY * v);
                    const float p = __expf(v - s_M[h]);
                    pp[h] = p;
                    lsum[h] += p;
                }
                offv = m << 9;                  // byte offset of X row
            } else {
                p4 = make_float4(0.0f, 0.0f, 0.0f, 0.0f);
                offv = 0;
            }
            s_p4[tid] = p4;
            s_off[tid] = offv;
        }
        if (tid < 16) {                         // zero pad for deep prefetch reads
            s_p4[plen + tid] = make_float4(0.0f, 0.0f, 0.0f, 0.0f);
            s_off[plen + tid] = 0;
        }
        __syncthreads();

        const int nit = plen >> 3;              // stages; each stage = 1 j per thread
        // pipeline prologue: stages 0 and 1 in regs, stage-2 offset ready
        float4 pv  = s_p4[jsub];
        float4 pvn = s_p4[jsub + 8];
        const int off1 = s_off[jsub + 8];
        int offA = s_off[jsub + 16];            // offset for stage i+2
        float4 xv  = xv_pre;
        float4 xvn = *(const float4*)(XbB + (unsigned)off1);

        for (int i = 0; i + 2 < nit; ++i) {
            const int jb = jsub + ((i + 2) << 3);
            const float4 xvnn = *(const float4*)(XbB + (unsigned)offA); // issue x(i+2)
            const float4 pvnn = s_p4[jb];                               // p(i+2)
            const int offB = s_off[jb + 8];                             // off(i+3)
            FMA16(pv, xv);                                              // compute stage i
            pv = pvn; pvn = pvnn;
            xv = xvn; xvn = xvnn;
            offA = offB;
        }
        FMA16(pv, xv);                          // last two stages (pads are p=0)
        FMA16(pvn, xvn);
        __syncthreads();
    }

    // ---- Phase 3: reductions + output ----
#pragma unroll
    for (int h = 0; h < H_HEADS; ++h) {
        float v = lsum[h];
#pragma unroll
        for (int off = 32; off > 0; off >>= 1) v += __shfl_xor(v, off);
        if (lane == 0) s_scr[wv * 4 + h] = v;
    }
    // intra-wave jsub-pair reduce, then one float4 write per (h, f4) from lanes<32
#pragma unroll
    for (int h = 0; h < 4; ++h)
#pragma unroll
        for (int fi = 0; fi < 4; ++fi)
            acc[h][fi] += __shfl_xor(acc[h][fi], 32);
    if (lane < 32) {
        float4* red4 = (float4*)s_red;
#pragma unroll
        for (int h = 0; h < 4; ++h)
            red4[wv * 128 + h * 32 + f4] =
                make_float4(acc[h][0], acc[h][1], acc[h][2], acc[h][3]);
    }
    __syncthreads();

    // outputs: thread writes 2 consecutive floats [2*tid, 2*tid+1]
    const int hf = tid * 2;
    const int h = tid >> 6;                     // == hf>>7
    const float l = s_scr[h] + s_scr[4 + h] + s_scr[8 + h] + s_scr[12 + h];
    const float invl = 1.0f / l;
    float v0 = 0.0f, v1 = 0.0f;
#pragma unroll
    for (int w = 0; w < 4; ++w) {
        v0 += s_red[w * 512 + hf];
        v1 += s_red[w * 512 + hf + 1];
    }
    float2 o;
    o.x = tanh_fast(v0 * invl);
    o.y = tanh_fast(v1 * invl);
    *(float2*)&out[(size_t)row * 512 + hf] = o;
}

extern "C" void kernel_launch(void* const* d_in, const int* in_sizes, int n_in,
                              void* d_out, int out_size, void* d_ws, size_t ws_size,
                              hipStream_t stream) {
    const float* X  = (const float*)d_in[0];
    const float* A  = (const float*)d_in[1];
    const float* wS = (const float*)d_in[2];
    const float* wN = (const float*)d_in[3];
    float* out = (float*)d_out;

    float* aSt = (float*)d_ws;                                  // B*N*H floats (packed)
    float* aNt = aSt + (size_t)B_BATCH * N_NODES * H_HEADS;     // B*N*H floats
    float* gmx = aNt + (size_t)B_BATCH * N_NODES * H_HEADS;     // B*H floats

    gat_proj<<<(B_BATCH * N_NODES) / 4, 256, 0, stream>>>(X, wS, wN, aSt, aNt);
    gat_gmax<<<B_BATCH, 256, 0, stream>>>(aNt, gmx);
    gat_main<<<B_BATCH * N_NODES, 256, 0, stream>>>(X, A, aSt, aNt, gmx, out);
}

// Round 2
// 105.638 us; speedup vs baseline: 1.1237x; 1.1237x over previous
//
#include <hip/hip_runtime.h>
#include <hip/hip_bf16.h>
#include <math.h>

#define N_NODES 2048
#define F_DIM   128
#define H_HEADS 4
#define B_BATCH 8
#define LEAKY   0.2f

__device__ __forceinline__ float tanh_fast(float x) {
    const float e = __expf(2.0f * x);
    return 1.0f - 2.0f / (e + 1.0f);
}

// ---------------- Kernel 1: projections, packed [b][n][h] ----------------
__global__ __launch_bounds__(256) void gat_proj(const float* __restrict__ X,
                                                const float* __restrict__ wS,
                                                const float* __restrict__ wN,
                                                float* __restrict__ aSt,
                                                float* __restrict__ aNt) {
    const int wave = threadIdx.x >> 6;
    const int lane = threadIdx.x & 63;
    const int row  = blockIdx.x * 4 + wave;            // b*N + n
    const float* xr = X + (size_t)row * F_DIM;
    const float x0 = xr[lane];
    const float x1 = xr[lane + 64];
    float4 ps4, pn4;
    float* psv = (float*)&ps4;
    float* pnv = (float*)&pn4;
#pragma unroll
    for (int h = 0; h < H_HEADS; ++h) {
        float ps = x0 * wS[h * F_DIM + lane] + x1 * wS[h * F_DIM + 64 + lane];
        float pn = x0 * wN[h * F_DIM + lane] + x1 * wN[h * F_DIM + 64 + lane];
#pragma unroll
        for (int off = 32; off > 0; off >>= 1) {
            ps += __shfl_xor(ps, off);
            pn += __shfl_xor(pn, off);
        }
        psv[h] = ps;
        pnv[h] = pn;
    }
    if (lane == 0) {
        ((float4*)aSt)[row] = ps4;
        ((float4*)aNt)[row] = pn4;
    }
}

// ---------------- Kernel 1b: per-(b,h) global max of a_neigh ----------------
__global__ __launch_bounds__(256) void gat_gmax(const float* __restrict__ aNt,
                                                float* __restrict__ gmax) {
    const int b = blockIdx.x;
    const int tid = threadIdx.x;
    const int lane = tid & 63;
    const int wv = tid >> 6;
    __shared__ float4 s_part[4];
    float4 m = make_float4(-1e30f, -1e30f, -1e30f, -1e30f);
    const float4* src = (const float4*)aNt + (size_t)b * N_NODES;
    for (int n = tid; n < N_NODES; n += 256) {
        const float4 v = src[n];
        m.x = fmaxf(m.x, v.x); m.y = fmaxf(m.y, v.y);
        m.z = fmaxf(m.z, v.z); m.w = fmaxf(m.w, v.w);
    }
#pragma unroll
    for (int off = 32; off > 0; off >>= 1) {
        m.x = fmaxf(m.x, __shfl_xor(m.x, off));
        m.y = fmaxf(m.y, __shfl_xor(m.y, off));
        m.z = fmaxf(m.z, __shfl_xor(m.z, off));
        m.w = fmaxf(m.w, __shfl_xor(m.w, off));
    }
    if (lane == 0) s_part[wv] = m;
    __syncthreads();
    if (tid == 0) {
        float4 r = s_part[0];
#pragma unroll
        for (int w = 1; w < 4; ++w) {
            r.x = fmaxf(r.x, s_part[w].x); r.y = fmaxf(r.y, s_part[w].y);
            r.z = fmaxf(r.z, s_part[w].z); r.w = fmaxf(r.w, s_part[w].w);
        }
        ((float4*)gmax)[b] = r;
    }
}

// 16-FMA microtile: 4 heads x 4 feature floats
#define FMA16(PV, XV)                                        \
    do {                                                     \
        acc[0][0] = fmaf((PV).x, (XV).x, acc[0][0]);         \
        acc[0][1] = fmaf((PV).x, (XV).y, acc[0][1]);         \
        acc[0][2] = fmaf((PV).x, (XV).z, acc[0][2]);         \
        acc[0][3] = fmaf((PV).x, (XV).w, acc[0][3]);         \
        acc[1][0] = fmaf((PV).y, (XV).x, acc[1][0]);         \
        acc[1][1] = fmaf((PV).y, (XV).y, acc[1][1]);         \
        acc[1][2] = fmaf((PV).y, (XV).z, acc[1][2]);         \
        acc[1][3] = fmaf((PV).y, (XV).w, acc[1][3]);         \
        acc[2][0] = fmaf((PV).z, (XV).x, acc[2][0]);         \
        acc[2][1] = fmaf((PV).z, (XV).y, acc[2][1]);         \
        acc[2][2] = fmaf((PV).z, (XV).z, acc[2][2]);         \
        acc[2][3] = fmaf((PV).z, (XV).w, acc[2][3]);         \
        acc[3][0] = fmaf((PV).w, (XV).x, acc[3][0]);         \
        acc[3][1] = fmaf((PV).w, (XV).y, acc[3][1]);         \
        acc[3][2] = fmaf((PV).w, (XV).z, acc[3][2]);         \
        acc[3][3] = fmaf((PV).w, (XV).w, acc[3][3]);         \
    } while (0)

// ---------------- Kernel 2: sparse softmax-gather per (b,n) row ----------------
__global__ __launch_bounds__(256, 6) void gat_main(const float* __restrict__ X,
                                                   const float* __restrict__ A,
                                                   const float* __restrict__ aSt,
                                                   const float* __restrict__ aNt,
                                                   const float* __restrict__ gmax,
                                                   float* __restrict__ out) {
    const int tid = threadIdx.x;
    const int row = blockIdx.x;                 // b*N + n
    const int b = row >> 11;
    const int lane = tid & 63;
    const int wv = tid >> 6;

    __shared__ short  s_idx[N_NODES];           // compacted neighbor indices (sorted)
    __shared__ float4 s_p4[256];                // p for chunk: [entry][head]
    __shared__ int    s_off[256];               // X-row byte offsets for chunk
    __shared__ float  s_red[4 * 512];           // per-wave partial sums
    __shared__ int    s_wtot[4];
    __shared__ float  s_M[4];
    __shared__ float  s_sv[4];
    __shared__ float  s_scr[16];                // [wv][h] lsum partials

    // ---- Phase 1: scan A row, prefix-sum compact nonzero columns ----
    const float4* Arow = (const float4*)(A + (size_t)row * N_NODES);
    const float4 a0 = Arow[tid * 2];
    const float4 a1 = Arow[tid * 2 + 1];

    // per-head shift constants (independent; overlaps A-load latency)
    if (tid < 4) {
        const float sv = aSt[(size_t)row * 4 + tid];
        const float g = gmax[b * 4 + tid];
        float v = sv + g;
        v = fmaxf(v, LEAKY * v);                // leaky, monotonic -> valid upper bound
        s_M[tid] = v;
        s_sv[tid] = sv;
    }

    const float av[8] = {a0.x, a0.y, a0.z, a0.w, a1.x, a1.y, a1.z, a1.w};
    int c = 0;
#pragma unroll
    for (int k = 0; k < 8; ++k) c += (av[k] != 0.0f) ? 1 : 0;

    int incl = c;
#pragma unroll
    for (int d = 1; d < 64; d <<= 1) {
        const int u = __shfl_up(incl, d);
        if (lane >= d) incl += u;
    }
    if (lane == 63) s_wtot[wv] = incl;
    __syncthreads();
    int wbase = 0;
#pragma unroll
    for (int w = 0; w < 4; ++w) wbase += (w < wv) ? s_wtot[w] : 0;
    const int cnt = s_wtot[0] + s_wtot[1] + s_wtot[2] + s_wtot[3];
    int pos = wbase + (incl - c);
#pragma unroll
    for (int k = 0; k < 8; ++k) {
        if (av[k] != 0.0f) s_idx[pos++] = (short)(tid * 8 + k);
    }
    __syncthreads();

    // ---- Phase 2: chunked p-generation + gather-accumulate ----
    float acc[4][4];
#pragma unroll
    for (int h = 0; h < 4; ++h)
#pragma unroll
        for (int fi = 0; fi < 4; ++fi) acc[h][fi] = 0.0f;
    float lsum[4] = {0.0f, 0.0f, 0.0f, 0.0f};

    const int jsub = tid >> 5;                  // 0..7
    const int f4 = tid & 31;                    // 0..31
    const char* XbB = (const char*)(X + (size_t)b * N_NODES * F_DIM) + (f4 << 4);
    const float4* aNb4 = (const float4*)aNt + (size_t)b * N_NODES;

    for (int base = 0; base < cnt; base += 256) {
        const int clen = min(256, cnt - base);
        if (tid < clen) {
            const int m = s_idx[base + tid];
            const float4 t = aNb4[m];
            const float tv[4] = {t.x, t.y, t.z, t.w};
            float4 p4;
            float* pp = (float*)&p4;
#pragma unroll
            for (int h = 0; h < H_HEADS; ++h) {
                float v = s_sv[h] + tv[h];
                v = fmaxf(v, LEAKY * v);
                const float p = __expf(v - s_M[h]);
                pp[h] = p;
                lsum[h] += p;
            }
            s_p4[tid] = p4;
            s_off[tid] = m << 9;                // byte offset of X row
        }
        __syncthreads();
#pragma unroll 4
        for (int j = jsub; j < clen; j += 8) {
            const float4 pv = s_p4[j];
            const float4 xv = *(const float4*)(XbB + (unsigned)s_off[j]);
            FMA16(pv, xv);
        }
        __syncthreads();
    }

    // ---- Phase 3: reductions + output ----
#pragma unroll
    for (int h = 0; h < H_HEADS; ++h) {
        float v = lsum[h];
#pragma unroll
        for (int off = 32; off > 0; off >>= 1) v += __shfl_xor(v, off);
        if (lane == 0) s_scr[wv * 4 + h] = v;
    }
    // intra-wave jsub-pair reduce, then one float4 write per (h, f4) from lanes<32
#pragma unroll
    for (int h = 0; h < 4; ++h)
#pragma unroll
        for (int fi = 0; fi < 4; ++fi)
            acc[h][fi] += __shfl_xor(acc[h][fi], 32);
    if (lane < 32) {
        float4* red4 = (float4*)s_red;
#pragma unroll
        for (int h = 0; h < 4; ++h)
            red4[wv * 128 + h * 32 + f4] =
                make_float4(acc[h][0], acc[h][1], acc[h][2], acc[h][3]);
    }
    __syncthreads();

    // outputs: thread writes 2 consecutive floats [2*tid, 2*tid+1]
    const int hf = tid * 2;
    const int h = tid >> 6;                     // == hf>>7
    const float l = s_scr[h] + s_scr[4 + h] + s_scr[8 + h] + s_scr[12 + h];
    const float invl = 1.0f / l;
    float v0 = 0.0f, v1 = 0.0f;
#pragma unroll
    for (int w = 0; w < 4; ++w) {
        v0 += s_red[w * 512 + hf];
        v1 += s_red[w * 512 + hf + 1];
    }
    float2 o;
    o.x = tanh_fast(v0 * invl);
    o.y = tanh_fast(v1 * invl);
    *(float2*)&out[(size_t)row * 512 + hf] = o;
}

extern "C" void kernel_launch(void* const* d_in, const int* in_sizes, int n_in,
                              void* d_out, int out_size, void* d_ws, size_t ws_size,
                              hipStream_t stream) {
    const float* X  = (const float*)d_in[0];
    const float* A  = (const float*)d_in[1];
    const float* wS = (const float*)d_in[2];
    const float* wN = (const float*)d_in[3];
    float* out = (float*)d_out;

    float* aSt = (float*)d_ws;                                  // B*N*H floats (packed)
    float* aNt = aSt + (size_t)B_BATCH * N_NODES * H_HEADS;     // B*N*H floats
    float* gmx = aNt + (size_t)B_BATCH * N_NODES * H_HEADS;     // B*H floats

    gat_proj<<<(B_BATCH * N_NODES) / 4, 256, 0, stream>>>(X, wS, wN, aSt, aNt);
    gat_gmax<<<B_BATCH, 256, 0, stream>>>(aNt, gmx);
    gat_main<<<B_BATCH * N_NODES, 256, 0, stream>>>(X, A, aSt, aNt, gmx, out);
}

// Round 3
// 102.779 us; speedup vs baseline: 1.1550x; 1.0278x over previous
//
#include <hip/hip_runtime.h>
#include <hip/hip_bf16.h>
#include <math.h>

#define N_NODES 2048
#define F_DIM   128
#define H_HEADS 4
#define B_BATCH 8
#define LEAKY   0.2f

typedef float f32x4 __attribute__((ext_vector_type(4)));
typedef float f32x2 __attribute__((ext_vector_type(2)));

__device__ __forceinline__ float tanh_fast(float x) {
    const float e = __expf(2.0f * x);
    return 1.0f - 2.0f / (e + 1.0f);
}

// ---------------- Kernel 1: projections, packed [b][n][h] ----------------
__global__ __launch_bounds__(256) void gat_proj(const float* __restrict__ X,
                                                const float* __restrict__ wS,
                                                const float* __restrict__ wN,
                                                float* __restrict__ aSt,
                                                float* __restrict__ aNt) {
    const int wave = threadIdx.x >> 6;
    const int lane = threadIdx.x & 63;
    const int row  = blockIdx.x * 4 + wave;            // b*N + n
    const float* xr = X + (size_t)row * F_DIM;
    const float x0 = xr[lane];
    const float x1 = xr[lane + 64];
    float4 ps4, pn4;
    float* psv = (float*)&ps4;
    float* pnv = (float*)&pn4;
#pragma unroll
    for (int h = 0; h < H_HEADS; ++h) {
        float ps = x0 * wS[h * F_DIM + lane] + x1 * wS[h * F_DIM + 64 + lane];
        float pn = x0 * wN[h * F_DIM + lane] + x1 * wN[h * F_DIM + 64 + lane];
#pragma unroll
        for (int off = 32; off > 0; off >>= 1) {
            ps += __shfl_xor(ps, off);
            pn += __shfl_xor(pn, off);
        }
        psv[h] = ps;
        pnv[h] = pn;
    }
    if (lane == 0) {
        ((float4*)aSt)[row] = ps4;
        ((float4*)aNt)[row] = pn4;
    }
}

// ---------------- Kernel 1b: per-(b,h) global max of a_neigh ----------------
__global__ __launch_bounds__(256) void gat_gmax(const float* __restrict__ aNt,
                                                float* __restrict__ gmax) {
    const int b = blockIdx.x;
    const int tid = threadIdx.x;
    const int lane = tid & 63;
    const int wv = tid >> 6;
    __shared__ float4 s_part[4];
    float4 m = make_float4(-1e30f, -1e30f, -1e30f, -1e30f);
    const float4* src = (const float4*)aNt + (size_t)b * N_NODES;
    for (int n = tid; n < N_NODES; n += 256) {
        const float4 v = src[n];
        m.x = fmaxf(m.x, v.x); m.y = fmaxf(m.y, v.y);
        m.z = fmaxf(m.z, v.z); m.w = fmaxf(m.w, v.w);
    }
#pragma unroll
    for (int off = 32; off > 0; off >>= 1) {
        m.x = fmaxf(m.x, __shfl_xor(m.x, off));
        m.y = fmaxf(m.y, __shfl_xor(m.y, off));
        m.z = fmaxf(m.z, __shfl_xor(m.z, off));
        m.w = fmaxf(m.w, __shfl_xor(m.w, off));
    }
    if (lane == 0) s_part[wv] = m;
    __syncthreads();
    if (tid == 0) {
        float4 r = s_part[0];
#pragma unroll
        for (int w = 1; w < 4; ++w) {
            r.x = fmaxf(r.x, s_part[w].x); r.y = fmaxf(r.y, s_part[w].y);
            r.z = fmaxf(r.z, s_part[w].z); r.w = fmaxf(r.w, s_part[w].w);
        }
        ((float4*)gmax)[b] = r;
    }
}

// 16-FMA microtile: 4 heads x 4 feature floats
#define FMA16(PV, XV)                                        \
    do {                                                     \
        acc[0][0] = fmaf((PV).x, (XV).x, acc[0][0]);         \
        acc[0][1] = fmaf((PV).x, (XV).y, acc[0][1]);         \
        acc[0][2] = fmaf((PV).x, (XV).z, acc[0][2]);         \
        acc[0][3] = fmaf((PV).x, (XV).w, acc[0][3]);         \
        acc[1][0] = fmaf((PV).y, (XV).x, acc[1][0]);         \
        acc[1][1] = fmaf((PV).y, (XV).y, acc[1][1]);         \
        acc[1][2] = fmaf((PV).y, (XV).z, acc[1][2]);         \
        acc[1][3] = fmaf((PV).y, (XV).w, acc[1][3]);         \
        acc[2][0] = fmaf((PV).z, (XV).x, acc[2][0]);         \
        acc[2][1] = fmaf((PV).z, (XV).y, acc[2][1]);         \
        acc[2][2] = fmaf((PV).z, (XV).z, acc[2][2]);         \
        acc[2][3] = fmaf((PV).z, (XV).w, acc[2][3]);         \
        acc[3][0] = fmaf((PV).w, (XV).x, acc[3][0]);         \
        acc[3][1] = fmaf((PV).w, (XV).y, acc[3][1]);         \
        acc[3][2] = fmaf((PV).w, (XV).z, acc[3][2]);         \
        acc[3][3] = fmaf((PV).w, (XV).w, acc[3][3]);         \
    } while (0)

// ---------------- Kernel 2: sparse softmax-gather per (b,n) row ----------------
__global__ __launch_bounds__(256, 6) void gat_main(const float* __restrict__ X,
                                                   const float* __restrict__ A,
                                                   const float* __restrict__ aSt,
                                                   const float* __restrict__ aNt,
                                                   const float* __restrict__ gmax,
                                                   float* __restrict__ out) {
    const int tid = threadIdx.x;
    // batch-per-XCD swizzle: round-robin dispatch sends bid%8 -> XCD id.
    // row = (bid&7)*2048 + bid>>3  => XCD k runs exactly batch k.
    // Gather working set per XCD becomes X_b (1 MB) + aNt_b (32 KB) << 4 MB L2.
    const int bid = blockIdx.x;
    const int row = ((bid & 7) << 11) | (bid >> 3);   // b*N + n
    const int b = row >> 11;
    const int lane = tid & 63;
    const int wv = tid >> 6;

    __shared__ short  s_idx[N_NODES];           // compacted neighbor indices (sorted)
    __shared__ float4 s_p4[256];                // p for chunk: [entry][head]
    __shared__ int    s_off[256];               // X-row byte offsets for chunk
    __shared__ float  s_red[4 * 512];           // per-wave partial sums
    __shared__ int    s_wtot[4];
    __shared__ float  s_M[4];
    __shared__ float  s_sv[4];
    __shared__ float  s_scr[16];                // [wv][h] lsum partials

    // ---- Phase 1: scan A row (non-temporal: zero reuse, don't evict X from L2) ----
    const f32x4* Arow = (const f32x4*)(A + (size_t)row * N_NODES);
    const f32x4 a0 = __builtin_nontemporal_load(Arow + tid * 2);
    const f32x4 a1 = __builtin_nontemporal_load(Arow + tid * 2 + 1);

    // per-head shift constants (independent; overlaps A-load latency)
    if (tid < 4) {
        const float sv = aSt[(size_t)row * 4 + tid];
        const float g = gmax[b * 4 + tid];
        float v = sv + g;
        v = fmaxf(v, LEAKY * v);                // leaky, monotonic -> valid upper bound
        s_M[tid] = v;
        s_sv[tid] = sv;
    }

    const float av[8] = {a0.x, a0.y, a0.z, a0.w, a1.x, a1.y, a1.z, a1.w};
    int c = 0;
#pragma unroll
    for (int k = 0; k < 8; ++k) c += (av[k] != 0.0f) ? 1 : 0;

    int incl = c;
#pragma unroll
    for (int d = 1; d < 64; d <<= 1) {
        const int u = __shfl_up(incl, d);
        if (lane >= d) incl += u;
    }
    if (lane == 63) s_wtot[wv] = incl;
    __syncthreads();
    int wbase = 0;
#pragma unroll
    for (int w = 0; w < 4; ++w) wbase += (w < wv) ? s_wtot[w] : 0;
    const int cnt = s_wtot[0] + s_wtot[1] + s_wtot[2] + s_wtot[3];
    int pos = wbase + (incl - c);
#pragma unroll
    for (int k = 0; k < 8; ++k) {
        if (av[k] != 0.0f) s_idx[pos++] = (short)(tid * 8 + k);
    }
    __syncthreads();

    // ---- Phase 2: chunked p-generation + gather-accumulate ----
    float acc[4][4];
#pragma unroll
    for (int h = 0; h < 4; ++h)
#pragma unroll
        for (int fi = 0; fi < 4; ++fi) acc[h][fi] = 0.0f;
    float lsum[4] = {0.0f, 0.0f, 0.0f, 0.0f};

    const int jsub = tid >> 5;                  // 0..7
    const int f4 = tid & 31;                    // 0..31
    const char* XbB = (const char*)(X + (size_t)b * N_NODES * F_DIM) + (f4 << 4);
    const float4* aNb4 = (const float4*)aNt + (size_t)b * N_NODES;

    for (int base = 0; base < cnt; base += 256) {
        const int clen = min(256, cnt - base);
        if (tid < clen) {
            const int m = s_idx[base + tid];
            const float4 t = aNb4[m];
            const float tv[4] = {t.x, t.y, t.z, t.w};
            float4 p4;
            float* pp = (float*)&p4;
#pragma unroll
            for (int h = 0; h < H_HEADS; ++h) {
                float v = s_sv[h] + tv[h];
                v = fmaxf(v, LEAKY * v);
                const float p = __expf(v - s_M[h]);
                pp[h] = p;
                lsum[h] += p;
            }
            s_p4[tid] = p4;
            s_off[tid] = m << 9;                // byte offset of X row
        }
        __syncthreads();
#pragma unroll 4
        for (int j = jsub; j < clen; j += 8) {
            const float4 pv = s_p4[j];
            const float4 xv = *(const float4*)(XbB + (unsigned)s_off[j]);
            FMA16(pv, xv);
        }
        __syncthreads();
    }

    // ---- Phase 3: reductions + output ----
#pragma unroll
    for (int h = 0; h < H_HEADS; ++h) {
        float v = lsum[h];
#pragma unroll
        for (int off = 32; off > 0; off >>= 1) v += __shfl_xor(v, off);
        if (lane == 0) s_scr[wv * 4 + h] = v;
    }
    // intra-wave jsub-pair reduce, then one float4 write per (h, f4) from lanes<32
#pragma unroll
    for (int h = 0; h < 4; ++h)
#pragma unroll
        for (int fi = 0; fi < 4; ++fi)
            acc[h][fi] += __shfl_xor(acc[h][fi], 32);
    if (lane < 32) {
        float4* red4 = (float4*)s_red;
#pragma unroll
        for (int h = 0; h < 4; ++h)
            red4[wv * 128 + h * 32 + f4] =
                make_float4(acc[h][0], acc[h][1], acc[h][2], acc[h][3]);
    }
    __syncthreads();

    // outputs: thread writes 2 consecutive floats [2*tid, 2*tid+1]
    const int hf = tid * 2;
    const int h = tid >> 6;                     // == hf>>7
    const float l = s_scr[h] + s_scr[4 + h] + s_scr[8 + h] + s_scr[12 + h];
    const float invl = 1.0f / l;
    float v0 = 0.0f, v1 = 0.0f;
#pragma unroll
    for (int w = 0; w < 4; ++w) {
        v0 += s_red[w * 512 + hf];
        v1 += s_red[w * 512 + hf + 1];
    }
    f32x2 o;
    o.x = tanh_fast(v0 * invl);
    o.y = tanh_fast(v1 * invl);
    __builtin_nontemporal_store(o, (f32x2*)&out[(size_t)row * 512 + hf]);
}

extern "C" void kernel_launch(void* const* d_in, const int* in_sizes, int n_in,
                              void* d_out, int out_size, void* d_ws, size_t ws_size,
                              hipStream_t stream) {
    const float* X  = (const float*)d_in[0];
    const float* A  = (const float*)d_in[1];
    const float* wS = (const float*)d_in[2];
    const float* wN = (const float*)d_in[3];
    float* out = (float*)d_out;

    float* aSt = (float*)d_ws;                                  // B*N*H floats (packed)
    float* aNt = aSt + (size_t)B_BATCH * N_NODES * H_HEADS;     // B*N*H floats
    float* gmx = aNt + (size_t)B_BATCH * N_NODES * H_HEADS;     // B*H floats

    gat_proj<<<(B_BATCH * N_NODES) / 4, 256, 0, stream>>>(X, wS, wN, aSt, aNt);
    gat_gmax<<<B_BATCH, 256, 0, stream>>>(aNt, gmx);
    gat_main<<<B_BATCH * N_NODES, 256, 0, stream>>>(X, A, aSt, aNt, gmx, out);
}